// Round 1
// baseline (197.072 us; speedup 1.0000x reference)
//
#include <hip/hip_runtime.h>

// Fast tanh: tanh(x) = 1 - 2/(e^{2x}+1), using v_exp_f32 (2^x) and v_rcp_f32.
// Saturates correctly: x -> +inf => e=inf => 1; x -> -inf => e=0 => -1.
static __device__ __forceinline__ float tanh_fast(float v) {
    float e = __builtin_amdgcn_exp2f(v * 2.8853900817779268f); // 2*log2(e)
    float r = __builtin_amdgcn_rcpf(e + 1.0f);
    return fmaf(-2.0f, r, 1.0f);
}

__global__ __launch_bounds__(256) void interior_kernel(
    const float2* __restrict__ x,
    const float*  __restrict__ imv,
    const float*  __restrict__ lmbd,
    const float*  __restrict__ Ww1, const float* __restrict__ bw1,
    const float*  __restrict__ Ww2, const float* __restrict__ bw2,
    const float*  __restrict__ Ww3, const float* __restrict__ bw3,
    const float*  __restrict__ Ww4, const float* __restrict__ bw4,
    const float*  __restrict__ Wp1, const float* __restrict__ bp1,
    const float*  __restrict__ Wp2, const float* __restrict__ bp2,
    const float*  __restrict__ Wp3, const float* __restrict__ bp3,
    const float*  __restrict__ Wp4, const float* __restrict__ bp4,
    float* __restrict__ out, int n)
{
    const int idx = blockIdx.x * blockDim.x + threadIdx.x;
    if (idx >= n) return;

    const float2 xv = x[idx];
    const float x0 = xv.x, x1 = xv.y;

    // ================= w-MLP: 2 -> 30 -> 30 -> 30 -> 8 =================
    float ha[30], hb[30];
    #pragma unroll
    for (int j = 0; j < 30; ++j)
        ha[j] = tanh_fast(fmaf(x1, Ww1[30 + j], fmaf(x0, Ww1[j], bw1[j])));

    #pragma unroll
    for (int j = 0; j < 30; ++j) hb[j] = bw2[j];
    #pragma unroll
    for (int i = 0; i < 30; ++i) {
        #pragma unroll
        for (int j = 0; j < 30; ++j)
            hb[j] = fmaf(ha[i], Ww2[i * 30 + j], hb[j]);
    }
    #pragma unroll
    for (int j = 0; j < 30; ++j) hb[j] = tanh_fast(hb[j]);

    #pragma unroll
    for (int j = 0; j < 30; ++j) ha[j] = bw3[j];
    #pragma unroll
    for (int i = 0; i < 30; ++i) {
        #pragma unroll
        for (int j = 0; j < 30; ++j)
            ha[j] = fmaf(hb[i], Ww3[i * 30 + j], ha[j]);
    }
    #pragma unroll
    for (int j = 0; j < 30; ++j) ha[j] = tanh_fast(ha[j]);

    float wv[8];
    #pragma unroll
    for (int j = 0; j < 8; ++j) wv[j] = bw4[j];
    #pragma unroll
    for (int i = 0; i < 30; ++i) {
        #pragma unroll
        for (int j = 0; j < 8; ++j)
            wv[j] = fmaf(ha[i], Ww4[i * 8 + j], wv[j]);
    }

    // ================= geometry about the interior vertex =================
    const float dx = x0 - imv[0], dy = x1 - imv[1];
    const float q  = fmaf(dx, dx, dy * dy);
    const float r  = sqrtf(q);
    const float ir = __builtin_amdgcn_rcpf(fmaxf(r, 1e-20f));
    const float u0 = dx * ir, u1 = dy * ir;   // x_ba (unit vector)

    // yita(r): t = clip(2.5r - 1.25, 0, 1); ((-6t+15)t-10)t^3 + 1
    const float t  = fminf(fmaxf(fmaf(2.5f, r, -1.25f), 0.0f), 1.0f);
    const float t3 = t * t * t;
    const float yv = fmaf(fmaf(fmaf(-6.0f, t, 15.0f), t, -10.0f), t3, 1.0f);

    // r^lambda via exp2(lam * log2(r))
    const float lam = lmbd[0];
    const float rl  = __builtin_amdgcn_exp2f(lam * __builtin_amdgcn_logf(fmaxf(r, 1e-20f)));

    // ================= phi-MLP: 2 -> 15 -> 15 -> 15 -> 4 =================
    float pa[15], pb[15];
    #pragma unroll
    for (int j = 0; j < 15; ++j)
        pa[j] = tanh_fast(fmaf(u1, Wp1[15 + j], fmaf(u0, Wp1[j], bp1[j])));

    #pragma unroll
    for (int j = 0; j < 15; ++j) pb[j] = bp2[j];
    #pragma unroll
    for (int i = 0; i < 15; ++i) {
        #pragma unroll
        for (int j = 0; j < 15; ++j)
            pb[j] = fmaf(pa[i], Wp2[i * 15 + j], pb[j]);
    }
    #pragma unroll
    for (int j = 0; j < 15; ++j) pb[j] = tanh_fast(pb[j]);

    #pragma unroll
    for (int j = 0; j < 15; ++j) pa[j] = bp3[j];
    #pragma unroll
    for (int i = 0; i < 15; ++i) {
        #pragma unroll
        for (int j = 0; j < 15; ++j)
            pa[j] = fmaf(pb[i], Wp3[i * 15 + j], pa[j]);
    }
    #pragma unroll
    for (int j = 0; j < 15; ++j) pa[j] = tanh_fast(pa[j]);

    float pv[4];
    #pragma unroll
    for (int j = 0; j < 4; ++j) pv[j] = bp4[j];
    #pragma unroll
    for (int i = 0; i < 15; ++i) {
        #pragma unroll
        for (int j = 0; j < 4; ++j)
            pv[j] = fmaf(pa[i], Wp4[i * 4 + j], pv[j]);
    }

    // ================= singular functions =================
    // At x: r0^k * sin(k*theta), k = 0.5, 1.0, 1.5, theta = atan2(x1, x0).
    // Half-angle forms: sin(t/2) = sign(y)*sqrt((1-c)/2), cos(t/2) = sqrt((1+c)/2),
    // sin(1.5t) = sin(t)cos(t/2) + cos(t)sin(t/2), with c = x0/r0, s = x1/r0.
    const float q0  = fmaf(x0, x0, x1 * x1);
    const float r0  = sqrtf(q0);
    const float ir0 = __builtin_amdgcn_rcpf(fmaxf(r0, 1e-20f));
    const float c0  = x0 * ir0;
    const float s0n = x1 * ir0;
    const float sr0 = sqrtf(r0);
    const float hc0 = sqrtf(fmaxf(0.0f, fmaf(0.5f, c0, 0.5f)));
    const float hs0 = copysignf(sqrtf(fmaxf(0.0f, fmaf(-0.5f, c0, 0.5f))), x1);
    const float vp0 = sr0 * hs0;                         // r^0.5 sin(0.5t)
    const float vp1 = x1;                                // r * sin(t) == y exactly
    const float vp2 = (r0 * sr0) * fmaf(s0n, hc0, c0 * hs0); // r^1.5 sin(1.5t)

    // At x_ba (unit vector, r == 1): c = u0, s = u1.
    const float hc2 = sqrtf(fmaxf(0.0f, fmaf(0.5f, u0, 0.5f)));
    const float hs2 = copysignf(sqrtf(fmaxf(0.0f, fmaf(-0.5f, u0, 0.5f))), u1);
    const float vs0 = hs2;
    const float vs1 = u1;
    const float vs2 = fmaf(u1, hc2, u0 * hs2);

    // ================= combine =================
    float rp = fmaf(yv, wv[4], wv[0]);
    rp = fmaf(fmaf(wv[5], yv, wv[1]), vp0, rp);
    rp = fmaf(fmaf(wv[6], yv, wv[2]), vp1, rp);
    rp = fmaf(fmaf(wv[7], yv, wv[3]), vp2, rp);

    float sacc = pv[0];
    sacc = fmaf(pv[1], vs0, sacc);
    sacc = fmaf(pv[2], vs1, sacc);
    sacc = fmaf(pv[3], vs2, sacc);

    out[idx] = fmaf(sacc * yv, rl, rp);
}

extern "C" void kernel_launch(void* const* d_in, const int* in_sizes, int n_in,
                              void* d_out, int out_size, void* d_ws, size_t ws_size,
                              hipStream_t stream) {
    const float2* x   = (const float2*)d_in[0];
    const float* imv  = (const float*)d_in[1];
    const float* lmbd = (const float*)d_in[2];
    const float* Ww1  = (const float*)d_in[3];
    const float* bw1  = (const float*)d_in[4];
    const float* Ww2  = (const float*)d_in[5];
    const float* bw2  = (const float*)d_in[6];
    const float* Ww3  = (const float*)d_in[7];
    const float* bw3  = (const float*)d_in[8];
    const float* bw4b = (const float*)d_in[10];
    const float* Ww4  = (const float*)d_in[9];
    const float* Wp1  = (const float*)d_in[11];
    const float* bp1  = (const float*)d_in[12];
    const float* Wp2  = (const float*)d_in[13];
    const float* bp2  = (const float*)d_in[14];
    const float* Wp3  = (const float*)d_in[15];
    const float* bp3  = (const float*)d_in[16];
    const float* Wp4  = (const float*)d_in[17];
    const float* bp4  = (const float*)d_in[18];
    float* out = (float*)d_out;

    const int n = in_sizes[0] / 2;
    const int block = 256;
    const int grid = (n + block - 1) / block;
    interior_kernel<<<grid, block, 0, stream>>>(
        x, imv, lmbd,
        Ww1, bw1, Ww2, bw2, Ww3, bw3, Ww4, bw4b,
        Wp1, bp1, Wp2, bp2, Wp3, bp3, Wp4, bp4,
        out, n);
}

// Round 2
// 177.831 us; speedup vs baseline: 1.1082x; 1.1082x over previous
//
#include <hip/hip_runtime.h>

typedef _Float16 half2_t __attribute__((ext_vector_type(2)));

#define CEXP 2.8853900817779268f  // 2*log2(e): tanh(z) = 1 - 2/(2^(c*z)+1)

// Prepped-weight storage (rewritten by prep_kernel on every launch).
__device__ float   g_w1s[60];    // c*Ww1  [2][30]
__device__ float   g_b1s[30];    // c*bw1
__device__ half2_t g_w2p[450];   // [j=30][kk=15]: {c*W2[2kk][j], c*W2[2kk+1][j]}
__device__ float   g_b2s[30];    // c*bw2
__device__ half2_t g_w3p[450];
__device__ float   g_b3s[30];
__device__ float   g_p1s[30];    // c*Wp1  [2][15]
__device__ float   g_bp1s[15];
__device__ half2_t g_p2p[120];   // [j=15][kk=8], kk=7 pair is {W[14][j], 0}
__device__ float   g_bp2s[15];
__device__ half2_t g_p3p[120];
__device__ float   g_bp3s[15];

static __device__ __forceinline__ float fdot2(half2_t a, half2_t b, float c) {
#if __has_builtin(__builtin_amdgcn_fdot2)
    return __builtin_amdgcn_fdot2(a, b, c, false);
#else
    return fmaf((float)a.x, (float)b.x, fmaf((float)a.y, (float)b.y, c));
#endif
}

// tanh with the 2*log2(e) factor pre-folded into the incoming accumulator.
static __device__ __forceinline__ float tanh_pre(float z) {
    float e = __builtin_amdgcn_exp2f(z);
    float r = __builtin_amdgcn_rcpf(e + 1.0f);
    return fmaf(-2.0f, r, 1.0f);
}

__global__ __launch_bounds__(256) void prep_kernel(
    const float* __restrict__ Ww1, const float* __restrict__ bw1,
    const float* __restrict__ Ww2, const float* __restrict__ bw2,
    const float* __restrict__ Ww3, const float* __restrict__ bw3,
    const float* __restrict__ Wp1, const float* __restrict__ bp1,
    const float* __restrict__ Wp2, const float* __restrict__ bp2,
    const float* __restrict__ Wp3, const float* __restrict__ bp3)
{
    const int t = threadIdx.x;
    const float c = CEXP;

    for (int e = t; e < 450; e += 256) {
        int j = e / 15, kk = e % 15;
        half2_t h2, h3;
        h2.x = (_Float16)(c * Ww2[(2 * kk) * 30 + j]);
        h2.y = (_Float16)(c * Ww2[(2 * kk + 1) * 30 + j]);
        h3.x = (_Float16)(c * Ww3[(2 * kk) * 30 + j]);
        h3.y = (_Float16)(c * Ww3[(2 * kk + 1) * 30 + j]);
        g_w2p[e] = h2;
        g_w3p[e] = h3;
    }
    for (int e = t; e < 120; e += 256) {
        int j = e / 8, kk = e % 8;
        int k0 = 2 * kk, k1 = 2 * kk + 1;
        half2_t h2, h3;
        h2.x = (_Float16)(c * Wp2[k0 * 15 + j]);
        h2.y = (k1 < 15) ? (_Float16)(c * Wp2[k1 * 15 + j]) : (_Float16)0.0f;
        h3.x = (_Float16)(c * Wp3[k0 * 15 + j]);
        h3.y = (k1 < 15) ? (_Float16)(c * Wp3[k1 * 15 + j]) : (_Float16)0.0f;
        g_p2p[e] = h2;
        g_p3p[e] = h3;
    }
    if (t < 60) g_w1s[t] = c * Ww1[t];
    if (t < 30) {
        g_b1s[t] = c * bw1[t];
        g_b2s[t] = c * bw2[t];
        g_b3s[t] = c * bw3[t];
        g_p1s[t] = c * Wp1[t];
    }
    if (t < 15) {
        g_bp1s[t] = c * bp1[t];
        g_bp2s[t] = c * bp2[t];
        g_bp3s[t] = c * bp3[t];
    }
}

__global__ __launch_bounds__(256, 4) void interior_kernel(
    const float2* __restrict__ x,
    const float*  __restrict__ imv,
    const float*  __restrict__ lmbd,
    const float*  __restrict__ Ww4, const float* __restrict__ bw4,
    const float*  __restrict__ Wp4, const float* __restrict__ bp4,
    float* __restrict__ out, int n)
{
    const int idx = blockIdx.x * blockDim.x + threadIdx.x;
    if (idx >= n) return;

    const float2 xv = x[idx];
    const float x0 = xv.x, x1 = xv.y;

    // ========== w-MLP layer 1 (f32, prescaled): 2 -> 30, tanh ==========
    float acc[30];
    #pragma unroll
    for (int j = 0; j < 30; ++j)
        acc[j] = tanh_pre(fmaf(x1, g_w1s[30 + j], fmaf(x0, g_w1s[j], g_b1s[j])));

    half2_t apk[15];
    #pragma unroll
    for (int kk = 0; kk < 15; ++kk)
        apk[kk] = half2_t{(_Float16)acc[2 * kk], (_Float16)acc[2 * kk + 1]};

    // ========== layer 2 (fp16 dot2, f32 accum): 30 -> 30, tanh ==========
    #pragma unroll
    for (int j = 0; j < 30; ++j) acc[j] = g_b2s[j];
    #pragma unroll
    for (int kk = 0; kk < 15; ++kk) {
        #pragma unroll
        for (int j = 0; j < 30; ++j)
            acc[j] = fdot2(apk[kk], g_w2p[j * 15 + kk], acc[j]);
    }
    #pragma unroll
    for (int j = 0; j < 30; ++j) acc[j] = tanh_pre(acc[j]);
    #pragma unroll
    for (int kk = 0; kk < 15; ++kk)
        apk[kk] = half2_t{(_Float16)acc[2 * kk], (_Float16)acc[2 * kk + 1]};

    // ========== layer 3 (fp16 dot2): 30 -> 30, tanh ==========
    #pragma unroll
    for (int j = 0; j < 30; ++j) acc[j] = g_b3s[j];
    #pragma unroll
    for (int kk = 0; kk < 15; ++kk) {
        #pragma unroll
        for (int j = 0; j < 30; ++j)
            acc[j] = fdot2(apk[kk], g_w3p[j * 15 + kk], acc[j]);
    }
    #pragma unroll
    for (int j = 0; j < 30; ++j) acc[j] = tanh_pre(acc[j]);

    // ========== layer 4 (f32, unscaled): 30 -> 8 ==========
    float wv[8];
    #pragma unroll
    for (int j = 0; j < 8; ++j) wv[j] = bw4[j];
    #pragma unroll
    for (int i = 0; i < 30; ++i) {
        #pragma unroll
        for (int j = 0; j < 8; ++j)
            wv[j] = fmaf(acc[i], Ww4[i * 8 + j], wv[j]);
    }

    // ========== geometry about the interior vertex ==========
    const float dx = x0 - imv[0], dy = x1 - imv[1];
    const float r  = sqrtf(fmaf(dx, dx, dy * dy));
    const float ir = __builtin_amdgcn_rcpf(fmaxf(r, 1e-20f));
    const float u0 = dx * ir, u1 = dy * ir;

    const float t  = fminf(fmaxf(fmaf(2.5f, r, -1.25f), 0.0f), 1.0f);
    const float t3 = t * t * t;
    const float yv = fmaf(fmaf(fmaf(-6.0f, t, 15.0f), t, -10.0f), t3, 1.0f);

    const float lam = lmbd[0];
    const float rl  = __builtin_amdgcn_exp2f(lam * __builtin_amdgcn_logf(fmaxf(r, 1e-20f)));

    // ========== phi-MLP layer 1 (f32, prescaled): 2 -> 15, tanh ==========
    float pacc[15];
    #pragma unroll
    for (int j = 0; j < 15; ++j)
        pacc[j] = tanh_pre(fmaf(u1, g_p1s[15 + j], fmaf(u0, g_p1s[j], g_bp1s[j])));

    half2_t ppk[8];
    #pragma unroll
    for (int kk = 0; kk < 7; ++kk)
        ppk[kk] = half2_t{(_Float16)pacc[2 * kk], (_Float16)pacc[2 * kk + 1]};
    ppk[7] = half2_t{(_Float16)pacc[14], (_Float16)0.0f};

    // ========== phi layer 2 (fp16 dot2): 15 -> 15, tanh ==========
    #pragma unroll
    for (int j = 0; j < 15; ++j) pacc[j] = g_bp2s[j];
    #pragma unroll
    for (int kk = 0; kk < 8; ++kk) {
        #pragma unroll
        for (int j = 0; j < 15; ++j)
            pacc[j] = fdot2(ppk[kk], g_p2p[j * 8 + kk], pacc[j]);
    }
    #pragma unroll
    for (int j = 0; j < 15; ++j) pacc[j] = tanh_pre(pacc[j]);
    #pragma unroll
    for (int kk = 0; kk < 7; ++kk)
        ppk[kk] = half2_t{(_Float16)pacc[2 * kk], (_Float16)pacc[2 * kk + 1]};
    ppk[7] = half2_t{(_Float16)pacc[14], (_Float16)0.0f};

    // ========== phi layer 3 (fp16 dot2): 15 -> 15, tanh ==========
    #pragma unroll
    for (int j = 0; j < 15; ++j) pacc[j] = g_bp3s[j];
    #pragma unroll
    for (int kk = 0; kk < 8; ++kk) {
        #pragma unroll
        for (int j = 0; j < 15; ++j)
            pacc[j] = fdot2(ppk[kk], g_p3p[j * 8 + kk], pacc[j]);
    }
    #pragma unroll
    for (int j = 0; j < 15; ++j) pacc[j] = tanh_pre(pacc[j]);

    // ========== phi layer 4 (f32): 15 -> 4 ==========
    float pv[4];
    #pragma unroll
    for (int j = 0; j < 4; ++j) pv[j] = bp4[j];
    #pragma unroll
    for (int i = 0; i < 15; ++i) {
        #pragma unroll
        for (int j = 0; j < 4; ++j)
            pv[j] = fmaf(pacc[i], Wp4[i * 4 + j], pv[j]);
    }

    // ========== singular functions ==========
    const float r0  = sqrtf(fmaf(x0, x0, x1 * x1));
    const float ir0 = __builtin_amdgcn_rcpf(fmaxf(r0, 1e-20f));
    const float c0  = x0 * ir0;
    const float s0n = x1 * ir0;
    const float sr0 = sqrtf(r0);
    const float hc0 = sqrtf(fmaxf(0.0f, fmaf(0.5f, c0, 0.5f)));
    const float hs0 = copysignf(sqrtf(fmaxf(0.0f, fmaf(-0.5f, c0, 0.5f))), x1);
    const float vp0 = sr0 * hs0;
    const float vp1 = x1;
    const float vp2 = (r0 * sr0) * fmaf(s0n, hc0, c0 * hs0);

    const float hc2 = sqrtf(fmaxf(0.0f, fmaf(0.5f, u0, 0.5f)));
    const float hs2 = copysignf(sqrtf(fmaxf(0.0f, fmaf(-0.5f, u0, 0.5f))), u1);
    const float vs0 = hs2;
    const float vs1 = u1;
    const float vs2 = fmaf(u1, hc2, u0 * hs2);

    // ========== combine ==========
    float rp = fmaf(yv, wv[4], wv[0]);
    rp = fmaf(fmaf(wv[5], yv, wv[1]), vp0, rp);
    rp = fmaf(fmaf(wv[6], yv, wv[2]), vp1, rp);
    rp = fmaf(fmaf(wv[7], yv, wv[3]), vp2, rp);

    float sacc = pv[0];
    sacc = fmaf(pv[1], vs0, sacc);
    sacc = fmaf(pv[2], vs1, sacc);
    sacc = fmaf(pv[3], vs2, sacc);

    out[idx] = fmaf(sacc * yv, rl, rp);
}

extern "C" void kernel_launch(void* const* d_in, const int* in_sizes, int n_in,
                              void* d_out, int out_size, void* d_ws, size_t ws_size,
                              hipStream_t stream) {
    const float2* x   = (const float2*)d_in[0];
    const float* imv  = (const float*)d_in[1];
    const float* lmbd = (const float*)d_in[2];
    const float* Ww1  = (const float*)d_in[3];
    const float* bw1  = (const float*)d_in[4];
    const float* Ww2  = (const float*)d_in[5];
    const float* bw2  = (const float*)d_in[6];
    const float* Ww3  = (const float*)d_in[7];
    const float* bw3  = (const float*)d_in[8];
    const float* Ww4  = (const float*)d_in[9];
    const float* bw4  = (const float*)d_in[10];
    const float* Wp1  = (const float*)d_in[11];
    const float* bp1  = (const float*)d_in[12];
    const float* Wp2  = (const float*)d_in[13];
    const float* bp2  = (const float*)d_in[14];
    const float* Wp3  = (const float*)d_in[15];
    const float* bp3  = (const float*)d_in[16];
    const float* Wp4  = (const float*)d_in[17];
    const float* bp4  = (const float*)d_in[18];
    float* out = (float*)d_out;

    const int n = in_sizes[0] / 2;

    prep_kernel<<<1, 256, 0, stream>>>(Ww1, bw1, Ww2, bw2, Ww3, bw3,
                                       Wp1, bp1, Wp2, bp2, Wp3, bp3);

    const int block = 256;
    const int grid = (n + block - 1) / block;
    interior_kernel<<<grid, block, 0, stream>>>(
        x, imv, lmbd, Ww4, bw4, Wp4, bp4, out, n);
}

// Round 3
// 174.263 us; speedup vs baseline: 1.1309x; 1.0205x over previous
//
#include <hip/hip_runtime.h>

typedef _Float16 half2_t __attribute__((ext_vector_type(2)));

#define CEXP 2.8853900817779268f  // 2*log2(e): tanh(z) = 1 - 2/(2^(c*z)+1)

// Prepped-weight storage (rewritten by prep_kernel on every launch).
__device__ float   g_w1s[60];    // c*Ww1  [2][30]
__device__ float   g_b1s[30];    // c*bw1
__device__ half2_t g_w2p[450];   // [j=30][kk=15]: {c*W2[2kk][j], c*W2[2kk+1][j]}
__device__ float   g_b2s[30];
__device__ half2_t g_w3p[450];
__device__ float   g_b3s[30];
__device__ half2_t g_w4p[120];   // [j=8][kk=15]: {W4[2kk][j], W4[2kk+1][j]} (unscaled)
__device__ float   g_p1s[30];    // c*Wp1  [2][15]
__device__ float   g_bp1s[15];
__device__ half2_t g_p2p[120];   // [j=15][kk=8], kk=7 pair {W[14][j], 0}
__device__ float   g_bp2s[15];
__device__ half2_t g_p3p[120];
__device__ float   g_bp3s[15];
__device__ half2_t g_p4p[32];    // [j=4][kk=8] (unscaled)

static __device__ __forceinline__ float fdot2(half2_t a, half2_t b, float c) {
#if __has_builtin(__builtin_amdgcn_fdot2)
    return __builtin_amdgcn_fdot2(a, b, c, false);
#else
    return fmaf((float)a.x, (float)b.x, fmaf((float)a.y, (float)b.y, c));
#endif
}

// tanh with the 2*log2(e) factor pre-folded into the incoming accumulator.
static __device__ __forceinline__ float tanh_pre(float z) {
    float e = __builtin_amdgcn_exp2f(z);
    float r = __builtin_amdgcn_rcpf(e + 1.0f);
    return fmaf(-2.0f, r, 1.0f);
}

__global__ __launch_bounds__(256) void prep_kernel(
    const float* __restrict__ Ww1, const float* __restrict__ bw1,
    const float* __restrict__ Ww2, const float* __restrict__ bw2,
    const float* __restrict__ Ww3, const float* __restrict__ bw3,
    const float* __restrict__ Ww4,
    const float* __restrict__ Wp1, const float* __restrict__ bp1,
    const float* __restrict__ Wp2, const float* __restrict__ bp2,
    const float* __restrict__ Wp3, const float* __restrict__ bp3,
    const float* __restrict__ Wp4)
{
    const int t = threadIdx.x;
    const float c = CEXP;

    for (int e = t; e < 450; e += 256) {
        int j = e / 15, kk = e % 15;
        half2_t h2, h3;
        h2.x = (_Float16)(c * Ww2[(2 * kk) * 30 + j]);
        h2.y = (_Float16)(c * Ww2[(2 * kk + 1) * 30 + j]);
        h3.x = (_Float16)(c * Ww3[(2 * kk) * 30 + j]);
        h3.y = (_Float16)(c * Ww3[(2 * kk + 1) * 30 + j]);
        g_w2p[e] = h2;
        g_w3p[e] = h3;
    }
    for (int e = t; e < 120; e += 256) {
        // w-MLP layer 4: [j=8][kk=15], unscaled
        int j4 = e / 15, kk4 = e % 15;
        half2_t h4;
        h4.x = (_Float16)Ww4[(2 * kk4) * 8 + j4];
        h4.y = (_Float16)Ww4[(2 * kk4 + 1) * 8 + j4];
        g_w4p[e] = h4;

        // phi layers 2/3: [j=15][kk=8]
        int j = e / 8, kk = e % 8;
        int k0 = 2 * kk, k1 = 2 * kk + 1;
        half2_t h2, h3;
        h2.x = (_Float16)(c * Wp2[k0 * 15 + j]);
        h2.y = (k1 < 15) ? (_Float16)(c * Wp2[k1 * 15 + j]) : (_Float16)0.0f;
        h3.x = (_Float16)(c * Wp3[k0 * 15 + j]);
        h3.y = (k1 < 15) ? (_Float16)(c * Wp3[k1 * 15 + j]) : (_Float16)0.0f;
        g_p2p[e] = h2;
        g_p3p[e] = h3;
    }
    if (t < 32) {
        // phi layer 4: [j=4][kk=8], unscaled
        int j = t / 8, kk = t % 8;
        int k0 = 2 * kk, k1 = 2 * kk + 1;
        half2_t h4;
        h4.x = (_Float16)Wp4[k0 * 4 + j];
        h4.y = (k1 < 15) ? (_Float16)Wp4[k1 * 4 + j] : (_Float16)0.0f;
        g_p4p[t] = h4;
    }
    if (t < 60) g_w1s[t] = c * Ww1[t];
    if (t < 30) {
        g_b1s[t] = c * bw1[t];
        g_b2s[t] = c * bw2[t];
        g_b3s[t] = c * bw3[t];
        g_p1s[t] = c * Wp1[t];
    }
    if (t < 15) {
        g_bp1s[t] = c * bp1[t];
        g_bp2s[t] = c * bp2[t];
        g_bp3s[t] = c * bp3[t];
    }
}

// 2 points per thread: every weight operand is fetched once and feeds two
// fdot2/fma ops, and the two independent chains double ILP per wave slot.
__global__ __launch_bounds__(256) void interior_kernel(
    const float4* __restrict__ x,      // two points per float4
    const float*  __restrict__ imv,
    const float*  __restrict__ lmbd,
    const float*  __restrict__ bw4,
    const float*  __restrict__ bp4,
    float* __restrict__ out, int n2)   // n2 = n/2
{
    const int idx = blockIdx.x * blockDim.x + threadIdx.x;
    if (idx >= n2) return;

    const float4 xx = x[idx];
    const float X0[2] = {xx.x, xx.z};
    const float X1[2] = {xx.y, xx.w};

    // ========== w-MLP layer 1 (f32, prescaled): 2 -> 30, tanh ==========
    float acc[2][30];
    #pragma unroll
    for (int j = 0; j < 30; ++j) {
        const float wa = g_w1s[j], wb = g_w1s[30 + j], bb = g_b1s[j];
        #pragma unroll
        for (int p = 0; p < 2; ++p)
            acc[p][j] = tanh_pre(fmaf(X1[p], wb, fmaf(X0[p], wa, bb)));
    }

    half2_t apk[2][15];
    #pragma unroll
    for (int p = 0; p < 2; ++p)
        #pragma unroll
        for (int kk = 0; kk < 15; ++kk)
            apk[p][kk] = half2_t{(_Float16)acc[p][2 * kk], (_Float16)acc[p][2 * kk + 1]};

    // ========== layer 2 (fp16 dot2, f32 accum): 30 -> 30, tanh ==========
    #pragma unroll
    for (int j = 0; j < 30; ++j) {
        const float bb = g_b2s[j];
        acc[0][j] = bb; acc[1][j] = bb;
    }
    #pragma unroll
    for (int kk = 0; kk < 15; ++kk) {
        #pragma unroll
        for (int j = 0; j < 30; ++j) {
            const half2_t w = g_w2p[j * 15 + kk];
            acc[0][j] = fdot2(apk[0][kk], w, acc[0][j]);
            acc[1][j] = fdot2(apk[1][kk], w, acc[1][j]);
        }
    }
    #pragma unroll
    for (int p = 0; p < 2; ++p) {
        #pragma unroll
        for (int j = 0; j < 30; ++j) acc[p][j] = tanh_pre(acc[p][j]);
        #pragma unroll
        for (int kk = 0; kk < 15; ++kk)
            apk[p][kk] = half2_t{(_Float16)acc[p][2 * kk], (_Float16)acc[p][2 * kk + 1]};
    }

    // ========== layer 3 (fp16 dot2): 30 -> 30, tanh ==========
    #pragma unroll
    for (int j = 0; j < 30; ++j) {
        const float bb = g_b3s[j];
        acc[0][j] = bb; acc[1][j] = bb;
    }
    #pragma unroll
    for (int kk = 0; kk < 15; ++kk) {
        #pragma unroll
        for (int j = 0; j < 30; ++j) {
            const half2_t w = g_w3p[j * 15 + kk];
            acc[0][j] = fdot2(apk[0][kk], w, acc[0][j]);
            acc[1][j] = fdot2(apk[1][kk], w, acc[1][j]);
        }
    }
    #pragma unroll
    for (int p = 0; p < 2; ++p) {
        #pragma unroll
        for (int j = 0; j < 30; ++j) acc[p][j] = tanh_pre(acc[p][j]);
        #pragma unroll
        for (int kk = 0; kk < 15; ++kk)
            apk[p][kk] = half2_t{(_Float16)acc[p][2 * kk], (_Float16)acc[p][2 * kk + 1]};
    }

    // ========== layer 4 (fp16 dot2, unscaled weights): 30 -> 8 ==========
    float wv[2][8];
    #pragma unroll
    for (int j = 0; j < 8; ++j) {
        const float bb = bw4[j];
        wv[0][j] = bb; wv[1][j] = bb;
    }
    #pragma unroll
    for (int kk = 0; kk < 15; ++kk) {
        #pragma unroll
        for (int j = 0; j < 8; ++j) {
            const half2_t w = g_w4p[j * 15 + kk];
            wv[0][j] = fdot2(apk[0][kk], w, wv[0][j]);
            wv[1][j] = fdot2(apk[1][kk], w, wv[1][j]);
        }
    }

    // ========== geometry ==========
    const float im0 = imv[0], im1 = imv[1], lam = lmbd[0];
    float U0[2], U1[2], YV[2], RL[2];
    #pragma unroll
    for (int p = 0; p < 2; ++p) {
        const float dx = X0[p] - im0, dy = X1[p] - im1;
        const float r  = sqrtf(fmaf(dx, dx, dy * dy));
        const float ir = __builtin_amdgcn_rcpf(fmaxf(r, 1e-20f));
        U0[p] = dx * ir; U1[p] = dy * ir;
        const float t  = fminf(fmaxf(fmaf(2.5f, r, -1.25f), 0.0f), 1.0f);
        const float t3 = t * t * t;
        YV[p] = fmaf(fmaf(fmaf(-6.0f, t, 15.0f), t, -10.0f), t3, 1.0f);
        RL[p] = __builtin_amdgcn_exp2f(lam * __builtin_amdgcn_logf(fmaxf(r, 1e-20f)));
    }

    // ========== phi-MLP layer 1 (f32, prescaled): 2 -> 15, tanh ==========
    float pacc[2][15];
    #pragma unroll
    for (int j = 0; j < 15; ++j) {
        const float wa = g_p1s[j], wb = g_p1s[15 + j], bb = g_bp1s[j];
        #pragma unroll
        for (int p = 0; p < 2; ++p)
            pacc[p][j] = tanh_pre(fmaf(U1[p], wb, fmaf(U0[p], wa, bb)));
    }

    half2_t ppk[2][8];
    #pragma unroll
    for (int p = 0; p < 2; ++p) {
        #pragma unroll
        for (int kk = 0; kk < 7; ++kk)
            ppk[p][kk] = half2_t{(_Float16)pacc[p][2 * kk], (_Float16)pacc[p][2 * kk + 1]};
        ppk[p][7] = half2_t{(_Float16)pacc[p][14], (_Float16)0.0f};
    }

    // ========== phi layer 2 (fp16 dot2): 15 -> 15, tanh ==========
    #pragma unroll
    for (int j = 0; j < 15; ++j) {
        const float bb = g_bp2s[j];
        pacc[0][j] = bb; pacc[1][j] = bb;
    }
    #pragma unroll
    for (int kk = 0; kk < 8; ++kk) {
        #pragma unroll
        for (int j = 0; j < 15; ++j) {
            const half2_t w = g_p2p[j * 8 + kk];
            pacc[0][j] = fdot2(ppk[0][kk], w, pacc[0][j]);
            pacc[1][j] = fdot2(ppk[1][kk], w, pacc[1][j]);
        }
    }
    #pragma unroll
    for (int p = 0; p < 2; ++p) {
        #pragma unroll
        for (int j = 0; j < 15; ++j) pacc[p][j] = tanh_pre(pacc[p][j]);
        #pragma unroll
        for (int kk = 0; kk < 7; ++kk)
            ppk[p][kk] = half2_t{(_Float16)pacc[p][2 * kk], (_Float16)pacc[p][2 * kk + 1]};
        ppk[p][7] = half2_t{(_Float16)pacc[p][14], (_Float16)0.0f};
    }

    // ========== phi layer 3 (fp16 dot2): 15 -> 15, tanh ==========
    #pragma unroll
    for (int j = 0; j < 15; ++j) {
        const float bb = g_bp3s[j];
        pacc[0][j] = bb; pacc[1][j] = bb;
    }
    #pragma unroll
    for (int kk = 0; kk < 8; ++kk) {
        #pragma unroll
        for (int j = 0; j < 15; ++j) {
            const half2_t w = g_p3p[j * 8 + kk];
            pacc[0][j] = fdot2(ppk[0][kk], w, pacc[0][j]);
            pacc[1][j] = fdot2(ppk[1][kk], w, pacc[1][j]);
        }
    }
    #pragma unroll
    for (int p = 0; p < 2; ++p) {
        #pragma unroll
        for (int j = 0; j < 15; ++j) pacc[p][j] = tanh_pre(pacc[p][j]);
        #pragma unroll
        for (int kk = 0; kk < 7; ++kk)
            ppk[p][kk] = half2_t{(_Float16)pacc[p][2 * kk], (_Float16)pacc[p][2 * kk + 1]};
        ppk[p][7] = half2_t{(_Float16)pacc[p][14], (_Float16)0.0f};
    }

    // ========== phi layer 4 (fp16 dot2, unscaled): 15 -> 4 ==========
    float pv[2][4];
    #pragma unroll
    for (int j = 0; j < 4; ++j) {
        const float bb = bp4[j];
        pv[0][j] = bb; pv[1][j] = bb;
    }
    #pragma unroll
    for (int kk = 0; kk < 8; ++kk) {
        #pragma unroll
        for (int j = 0; j < 4; ++j) {
            const half2_t w = g_p4p[j * 8 + kk];
            pv[0][j] = fdot2(ppk[0][kk], w, pv[0][j]);
            pv[1][j] = fdot2(ppk[1][kk], w, pv[1][j]);
        }
    }

    // ========== singular functions + combine ==========
    float res[2];
    #pragma unroll
    for (int p = 0; p < 2; ++p) {
        const float x0 = X0[p], x1 = X1[p];
        const float r0  = sqrtf(fmaf(x0, x0, x1 * x1));
        const float ir0 = __builtin_amdgcn_rcpf(fmaxf(r0, 1e-20f));
        const float c0  = x0 * ir0;
        const float s0n = x1 * ir0;
        const float sr0 = sqrtf(r0);
        const float hc0 = sqrtf(fmaxf(0.0f, fmaf(0.5f, c0, 0.5f)));
        const float hs0 = copysignf(sqrtf(fmaxf(0.0f, fmaf(-0.5f, c0, 0.5f))), x1);
        const float vp0 = sr0 * hs0;
        const float vp1 = x1;
        const float vp2 = (r0 * sr0) * fmaf(s0n, hc0, c0 * hs0);

        const float u0 = U0[p], u1 = U1[p], yv = YV[p];
        const float hc2 = sqrtf(fmaxf(0.0f, fmaf(0.5f, u0, 0.5f)));
        const float hs2 = copysignf(sqrtf(fmaxf(0.0f, fmaf(-0.5f, u0, 0.5f))), u1);
        const float vs0 = hs2;
        const float vs1 = u1;
        const float vs2 = fmaf(u1, hc2, u0 * hs2);

        float rp = fmaf(yv, wv[p][4], wv[p][0]);
        rp = fmaf(fmaf(wv[p][5], yv, wv[p][1]), vp0, rp);
        rp = fmaf(fmaf(wv[p][6], yv, wv[p][2]), vp1, rp);
        rp = fmaf(fmaf(wv[p][7], yv, wv[p][3]), vp2, rp);

        float sacc = pv[p][0];
        sacc = fmaf(pv[p][1], vs0, sacc);
        sacc = fmaf(pv[p][2], vs1, sacc);
        sacc = fmaf(pv[p][3], vs2, sacc);

        res[p] = fmaf(sacc * yv, RL[p], rp);
    }

    // contiguous pair store
    float2 o; o.x = res[0]; o.y = res[1];
    ((float2*)out)[idx] = o;
}

extern "C" void kernel_launch(void* const* d_in, const int* in_sizes, int n_in,
                              void* d_out, int out_size, void* d_ws, size_t ws_size,
                              hipStream_t stream) {
    const float4* x   = (const float4*)d_in[0];
    const float* imv  = (const float*)d_in[1];
    const float* lmbd = (const float*)d_in[2];
    const float* Ww1  = (const float*)d_in[3];
    const float* bw1  = (const float*)d_in[4];
    const float* Ww2  = (const float*)d_in[5];
    const float* bw2  = (const float*)d_in[6];
    const float* Ww3  = (const float*)d_in[7];
    const float* bw3  = (const float*)d_in[8];
    const float* Ww4  = (const float*)d_in[9];
    const float* bw4  = (const float*)d_in[10];
    const float* Wp1  = (const float*)d_in[11];
    const float* bp1  = (const float*)d_in[12];
    const float* Wp2  = (const float*)d_in[13];
    const float* bp2  = (const float*)d_in[14];
    const float* Wp3  = (const float*)d_in[15];
    const float* bp3  = (const float*)d_in[16];
    const float* Wp4  = (const float*)d_in[17];
    const float* bp4  = (const float*)d_in[18];
    float* out = (float*)d_out;

    const int n  = in_sizes[0] / 2;
    const int n2 = n / 2;

    prep_kernel<<<1, 256, 0, stream>>>(Ww1, bw1, Ww2, bw2, Ww3, bw3, Ww4,
                                       Wp1, bp1, Wp2, bp2, Wp3, bp3, Wp4);

    const int block = 256;
    const int grid = (n2 + block - 1) / block;
    interior_kernel<<<grid, block, 0, stream>>>(
        x, imv, lmbd, bw4, bp4, out, n2);
}

// Round 5
// 171.971 us; speedup vs baseline: 1.1460x; 1.0133x over previous
//
#include <hip/hip_runtime.h>

typedef _Float16 half2_t __attribute__((ext_vector_type(2)));

#define CEXP 2.8853900817779268f  // 2*log2(e): tanh(z) = 1 - 2/(2^(c*z)+1)

// Prepped-weight storage (rewritten by prep_kernel on every launch).
// All matrices stored [kk][j] so the unrolled j-inner loop reads consecutive
// dwords -> backend merges uniform loads into s_load_dwordx8/16.
__device__ float   g_w1s[60];    // c*Ww1  [2][30]
__device__ float   g_b1s[30];    // c*bw1
__device__ half2_t g_w2p[450];   // [kk=15][j=30]: {c*W2[2kk][j], c*W2[2kk+1][j]}
__device__ float   g_b2s[30];
__device__ half2_t g_w3p[450];   // [kk=15][j=30]
__device__ float   g_b3s[30];
__device__ half2_t g_w4p[120];   // [kk=15][j=8] (unscaled)
__device__ float   g_p1s[30];    // c*Wp1  [2][15]
__device__ float   g_bp1s[15];
__device__ half2_t g_p2p[120];   // [kk=8][j=15], kk=7 pair {W[14][j], 0}
__device__ float   g_bp2s[15];
__device__ half2_t g_p3p[120];   // [kk=8][j=15]
__device__ float   g_bp3s[15];
__device__ half2_t g_p4p[32];    // [kk=8][j=4] (unscaled)

static __device__ __forceinline__ float fdot2(half2_t a, half2_t b, float c) {
#if __has_builtin(__builtin_amdgcn_fdot2)
    return __builtin_amdgcn_fdot2(a, b, c, false);
#else
    return fmaf((float)a.x, (float)b.x, fmaf((float)a.y, (float)b.y, c));
#endif
}

static __device__ __forceinline__ half2_t pkrtz(float a, float b) {
    return __builtin_bit_cast(half2_t, __builtin_amdgcn_cvt_pkrtz(a, b));
}

// tanh with the 2*log2(e) factor pre-folded into the incoming accumulator.
static __device__ __forceinline__ float tanh_pre(float z) {
    float e = __builtin_amdgcn_exp2f(z);
    float r = __builtin_amdgcn_rcpf(e + 1.0f);
    return fmaf(-2.0f, r, 1.0f);
}

__global__ __launch_bounds__(256) void prep_kernel(
    const float* __restrict__ Ww1, const float* __restrict__ bw1,
    const float* __restrict__ Ww2, const float* __restrict__ bw2,
    const float* __restrict__ Ww3, const float* __restrict__ bw3,
    const float* __restrict__ Ww4,
    const float* __restrict__ Wp1, const float* __restrict__ bp1,
    const float* __restrict__ Wp2, const float* __restrict__ bp2,
    const float* __restrict__ Wp3, const float* __restrict__ bp3,
    const float* __restrict__ Wp4)
{
    const int t = threadIdx.x;
    const float c = CEXP;

    for (int e = t; e < 450; e += 256) {
        int kk = e / 30, j = e % 30;
        half2_t h2, h3;
        h2.x = (_Float16)(c * Ww2[(2 * kk) * 30 + j]);
        h2.y = (_Float16)(c * Ww2[(2 * kk + 1) * 30 + j]);
        h3.x = (_Float16)(c * Ww3[(2 * kk) * 30 + j]);
        h3.y = (_Float16)(c * Ww3[(2 * kk + 1) * 30 + j]);
        g_w2p[e] = h2;   // index kk*30 + j
        g_w3p[e] = h3;
    }
    for (int e = t; e < 120; e += 256) {
        // w-MLP layer 4: [kk=15][j=8], unscaled
        int kk4 = e / 8, j4 = e % 8;
        half2_t h4;
        h4.x = (_Float16)Ww4[(2 * kk4) * 8 + j4];
        h4.y = (_Float16)Ww4[(2 * kk4 + 1) * 8 + j4];
        g_w4p[e] = h4;   // index kk4*8 + j4

        // phi layers 2/3: [kk=8][j=15]
        int kk = e / 15, j = e % 15;
        int k0 = 2 * kk, k1 = 2 * kk + 1;
        half2_t h2, h3;
        h2.x = (_Float16)(c * Wp2[k0 * 15 + j]);
        h2.y = (k1 < 15) ? (_Float16)(c * Wp2[k1 * 15 + j]) : (_Float16)0.0f;
        h3.x = (_Float16)(c * Wp3[k0 * 15 + j]);
        h3.y = (k1 < 15) ? (_Float16)(c * Wp3[k1 * 15 + j]) : (_Float16)0.0f;
        g_p2p[e] = h2;   // index kk*15 + j
        g_p3p[e] = h3;
    }
    if (t < 32) {
        // phi layer 4: [kk=8][j=4], unscaled
        int kk = t / 4, j = t % 4;
        int k0 = 2 * kk, k1 = 2 * kk + 1;
        half2_t h4;
        h4.x = (_Float16)Wp4[k0 * 4 + j];
        h4.y = (k1 < 15) ? (_Float16)Wp4[k1 * 4 + j] : (_Float16)0.0f;
        g_p4p[t] = h4;
    }
    if (t < 60) g_w1s[t] = c * Ww1[t];
    if (t < 30) {
        g_b1s[t] = c * bw1[t];
        g_b2s[t] = c * bw2[t];
        g_b3s[t] = c * bw3[t];
        g_p1s[t] = c * Wp1[t];
    }
    if (t < 15) {
        g_bp1s[t] = c * bp1[t];
        g_bp2s[t] = c * bp2[t];
        g_bp3s[t] = c * bp3[t];
    }
}

// 2 points per thread; 30-wide layers processed in j-halves (16+14) to keep
// the live register set ~75 < the 128-VGPR cap from __launch_bounds__(256,4).
__global__ __launch_bounds__(256, 4) void interior_kernel(
    const float4* __restrict__ x,      // two points per float4
    const float*  __restrict__ imv,
    const float*  __restrict__ lmbd,
    const float*  __restrict__ bw4,
    const float*  __restrict__ bp4,
    float* __restrict__ out, int n2)   // n2 = n/2
{
    const int idx = blockIdx.x * blockDim.x + threadIdx.x;
    if (idx >= n2) return;

    const float4 xx = x[idx];
    const float X0[2] = {xx.x, xx.z};
    const float X1[2] = {xx.y, xx.w};

    // ========== w-MLP layer 1 (f32, prescaled): 2 -> 30, tanh, pack ==========
    half2_t apk[2][15];
    #pragma unroll
    for (int jj = 0; jj < 15; ++jj) {
        const int j0 = 2 * jj, j1 = 2 * jj + 1;
        const float wa0 = g_w1s[j0], wb0 = g_w1s[30 + j0], bb0 = g_b1s[j0];
        const float wa1 = g_w1s[j1], wb1 = g_w1s[30 + j1], bb1 = g_b1s[j1];
        #pragma unroll
        for (int p = 0; p < 2; ++p) {
            const float t0 = tanh_pre(fmaf(X1[p], wb0, fmaf(X0[p], wa0, bb0)));
            const float t1 = tanh_pre(fmaf(X1[p], wb1, fmaf(X0[p], wa1, bb1)));
            apk[p][jj] = pkrtz(t0, t1);
        }
    }

    // ========== layers 2 and 3 (fp16 dot2, f32 accum), j-halved ==========
    half2_t bpk[2][15];
    #pragma unroll
    for (int layer = 0; layer < 2; ++layer) {
        const half2_t* __restrict__ W = layer ? g_w3p : g_w2p;
        const float*   __restrict__ B = layer ? g_b3s : g_b2s;

        // ---- half 0: j = 0..15 ----
        {
            float a16[2][16];
            #pragma unroll
            for (int j = 0; j < 16; ++j) {
                const float bb = B[j];
                a16[0][j] = bb; a16[1][j] = bb;
            }
            #pragma unroll
            for (int kk = 0; kk < 15; ++kk) {
                #pragma unroll
                for (int j = 0; j < 16; ++j) {
                    const half2_t w = W[kk * 30 + j];
                    a16[0][j] = fdot2(apk[0][kk], w, a16[0][j]);
                    a16[1][j] = fdot2(apk[1][kk], w, a16[1][j]);
                }
            }
            #pragma unroll
            for (int p = 0; p < 2; ++p)
                #pragma unroll
                for (int jj = 0; jj < 8; ++jj)
                    bpk[p][jj] = pkrtz(tanh_pre(a16[p][2 * jj]),
                                       tanh_pre(a16[p][2 * jj + 1]));
        }
        // ---- half 1: j = 16..29 ----
        {
            float a14[2][14];
            #pragma unroll
            for (int j = 0; j < 14; ++j) {
                const float bb = B[16 + j];
                a14[0][j] = bb; a14[1][j] = bb;
            }
            #pragma unroll
            for (int kk = 0; kk < 15; ++kk) {
                #pragma unroll
                for (int j = 0; j < 14; ++j) {
                    const half2_t w = W[kk * 30 + 16 + j];
                    a14[0][j] = fdot2(apk[0][kk], w, a14[0][j]);
                    a14[1][j] = fdot2(apk[1][kk], w, a14[1][j]);
                }
            }
            #pragma unroll
            for (int p = 0; p < 2; ++p)
                #pragma unroll
                for (int jj = 0; jj < 7; ++jj)
                    bpk[p][8 + jj] = pkrtz(tanh_pre(a14[p][2 * jj]),
                                           tanh_pre(a14[p][2 * jj + 1]));
        }
        // feed next layer
        #pragma unroll
        for (int p = 0; p < 2; ++p)
            #pragma unroll
            for (int kk = 0; kk < 15; ++kk)
                apk[p][kk] = bpk[p][kk];
    }

    // ========== layer 4 (fp16 dot2, unscaled): 30 -> 8 ==========
    float wv[2][8];
    #pragma unroll
    for (int j = 0; j < 8; ++j) {
        const float bb = bw4[j];
        wv[0][j] = bb; wv[1][j] = bb;
    }
    #pragma unroll
    for (int kk = 0; kk < 15; ++kk) {
        #pragma unroll
        for (int j = 0; j < 8; ++j) {
            const half2_t w = g_w4p[kk * 8 + j];
            wv[0][j] = fdot2(apk[0][kk], w, wv[0][j]);
            wv[1][j] = fdot2(apk[1][kk], w, wv[1][j]);
        }
    }

    // ========== geometry ==========
    const float im0 = imv[0], im1 = imv[1], lam = lmbd[0];
    float U0[2], U1[2], YV[2], RL[2];
    #pragma unroll
    for (int p = 0; p < 2; ++p) {
        const float dx = X0[p] - im0, dy = X1[p] - im1;
        const float r  = sqrtf(fmaf(dx, dx, dy * dy));
        const float ir = __builtin_amdgcn_rcpf(fmaxf(r, 1e-20f));
        U0[p] = dx * ir; U1[p] = dy * ir;
        const float t  = fminf(fmaxf(fmaf(2.5f, r, -1.25f), 0.0f), 1.0f);
        const float t3 = t * t * t;
        YV[p] = fmaf(fmaf(fmaf(-6.0f, t, 15.0f), t, -10.0f), t3, 1.0f);
        RL[p] = __builtin_amdgcn_exp2f(lam * __builtin_amdgcn_logf(fmaxf(r, 1e-20f)));
    }

    // ========== phi-MLP layer 1 (f32, prescaled): 2 -> 15, tanh, pack ==========
    half2_t ppk[2][8];
    #pragma unroll
    for (int jj = 0; jj < 7; ++jj) {
        const int j0 = 2 * jj, j1 = 2 * jj + 1;
        const float wa0 = g_p1s[j0], wb0 = g_p1s[15 + j0], bb0 = g_bp1s[j0];
        const float wa1 = g_p1s[j1], wb1 = g_p1s[15 + j1], bb1 = g_bp1s[j1];
        #pragma unroll
        for (int p = 0; p < 2; ++p) {
            const float t0 = tanh_pre(fmaf(U1[p], wb0, fmaf(U0[p], wa0, bb0)));
            const float t1 = tanh_pre(fmaf(U1[p], wb1, fmaf(U0[p], wa1, bb1)));
            ppk[p][jj] = pkrtz(t0, t1);
        }
    }
    {
        const float wa = g_p1s[14], wb = g_p1s[29], bb = g_bp1s[14];
        #pragma unroll
        for (int p = 0; p < 2; ++p) {
            const float t0 = tanh_pre(fmaf(U1[p], wb, fmaf(U0[p], wa, bb)));
            ppk[p][7] = pkrtz(t0, 0.0f);
        }
    }

    // ========== phi layers 2 and 3 (fp16 dot2): 15 -> 15 ==========
    half2_t qpk[2][8];
    #pragma unroll
    for (int layer = 0; layer < 2; ++layer) {
        const half2_t* __restrict__ W = layer ? g_p3p : g_p2p;
        const float*   __restrict__ B = layer ? g_bp3s : g_bp2s;

        float a15[2][15];
        #pragma unroll
        for (int j = 0; j < 15; ++j) {
            const float bb = B[j];
            a15[0][j] = bb; a15[1][j] = bb;
        }
        #pragma unroll
        for (int kk = 0; kk < 8; ++kk) {
            #pragma unroll
            for (int j = 0; j < 15; ++j) {
                const half2_t w = W[kk * 15 + j];
                a15[0][j] = fdot2(ppk[0][kk], w, a15[0][j]);
                a15[1][j] = fdot2(ppk[1][kk], w, a15[1][j]);
            }
        }
        #pragma unroll
        for (int p = 0; p < 2; ++p) {
            #pragma unroll
            for (int jj = 0; jj < 7; ++jj)
                qpk[p][jj] = pkrtz(tanh_pre(a15[p][2 * jj]),
                                   tanh_pre(a15[p][2 * jj + 1]));
            qpk[p][7] = pkrtz(tanh_pre(a15[p][14]), 0.0f);
        }
        #pragma unroll
        for (int p = 0; p < 2; ++p)
            #pragma unroll
            for (int kk = 0; kk < 8; ++kk)
                ppk[p][kk] = qpk[p][kk];
    }

    // ========== phi layer 4 (fp16 dot2, unscaled): 15 -> 4 ==========
    float pv[2][4];
    #pragma unroll
    for (int j = 0; j < 4; ++j) {
        const float bb = bp4[j];
        pv[0][j] = bb; pv[1][j] = bb;
    }
    #pragma unroll
    for (int kk = 0; kk < 8; ++kk) {
        #pragma unroll
        for (int j = 0; j < 4; ++j) {
            const half2_t w = g_p4p[kk * 4 + j];
            pv[0][j] = fdot2(ppk[0][kk], w, pv[0][j]);
            pv[1][j] = fdot2(ppk[1][kk], w, pv[1][j]);
        }
    }

    // ========== singular functions + combine ==========
    float res[2];
    #pragma unroll
    for (int p = 0; p < 2; ++p) {
        const float x0 = X0[p], x1 = X1[p];
        const float r0  = sqrtf(fmaf(x0, x0, x1 * x1));
        const float ir0 = __builtin_amdgcn_rcpf(fmaxf(r0, 1e-20f));
        const float c0  = x0 * ir0;
        const float s0n = x1 * ir0;
        const float sr0 = sqrtf(r0);
        const float hc0 = sqrtf(fmaxf(0.0f, fmaf(0.5f, c0, 0.5f)));
        const float hs0 = copysignf(sqrtf(fmaxf(0.0f, fmaf(-0.5f, c0, 0.5f))), x1);
        const float vp0 = sr0 * hs0;
        const float vp1 = x1;
        const float vp2 = (r0 * sr0) * fmaf(s0n, hc0, c0 * hs0);

        const float u0 = U0[p], u1 = U1[p], yv = YV[p];
        const float hc2 = sqrtf(fmaxf(0.0f, fmaf(0.5f, u0, 0.5f)));
        const float hs2 = copysignf(sqrtf(fmaxf(0.0f, fmaf(-0.5f, u0, 0.5f))), u1);
        const float vs0 = hs2;
        const float vs1 = u1;
        const float vs2 = fmaf(u1, hc2, u0 * hs2);

        float rp = fmaf(yv, wv[p][4], wv[p][0]);
        rp = fmaf(fmaf(wv[p][5], yv, wv[p][1]), vp0, rp);
        rp = fmaf(fmaf(wv[p][6], yv, wv[p][2]), vp1, rp);
        rp = fmaf(fmaf(wv[p][7], yv, wv[p][3]), vp2, rp);

        float sacc = pv[p][0];
        sacc = fmaf(pv[p][1], vs0, sacc);
        sacc = fmaf(pv[p][2], vs1, sacc);
        sacc = fmaf(pv[p][3], vs2, sacc);

        res[p] = fmaf(sacc * yv, RL[p], rp);
    }

    // contiguous pair store
    float2 o; o.x = res[0]; o.y = res[1];
    ((float2*)out)[idx] = o;
}

extern "C" void kernel_launch(void* const* d_in, const int* in_sizes, int n_in,
                              void* d_out, int out_size, void* d_ws, size_t ws_size,
                              hipStream_t stream) {
    const float4* x   = (const float4*)d_in[0];
    const float* imv  = (const float*)d_in[1];
    const float* lmbd = (const float*)d_in[2];
    const float* Ww1  = (const float*)d_in[3];
    const float* bw1  = (const float*)d_in[4];
    const float* Ww2  = (const float*)d_in[5];
    const float* bw2  = (const float*)d_in[6];
    const float* Ww3  = (const float*)d_in[7];
    const float* bw3  = (const float*)d_in[8];
    const float* Ww4  = (const float*)d_in[9];
    const float* bw4  = (const float*)d_in[10];
    const float* Wp1  = (const float*)d_in[11];
    const float* bp1  = (const float*)d_in[12];
    const float* Wp2  = (const float*)d_in[13];
    const float* bp2  = (const float*)d_in[14];
    const float* Wp3  = (const float*)d_in[15];
    const float* bp3  = (const float*)d_in[16];
    const float* Wp4  = (const float*)d_in[17];
    const float* bp4  = (const float*)d_in[18];
    float* out = (float*)d_out;

    const int n  = in_sizes[0] / 2;
    const int n2 = n / 2;

    prep_kernel<<<1, 256, 0, stream>>>(Ww1, bw1, Ww2, bw2, Ww3, bw3, Ww4,
                                       Wp1, bp1, Wp2, bp2, Wp3, bp3, Wp4);

    const int block = 256;
    const int grid = (n2 + block - 1) / block;
    interior_kernel<<<grid, block, 0, stream>>>(
        x, imv, lmbd, bw4, bp4, out, n2);
}